// Round 6
// baseline (180.694 us; speedup 1.0000x reference)
//
#include <hip/hip_runtime.h>
#include <stdint.h>

// Problem dims
#define TDIM 4096
#define HDIM 2048   // N and K of the GEMM

// GEMM tile
#define BM 256
#define BN 128
#define BK 64
#define NKT (HDIM / BK)   // 32
// LDS: per buffer = B region only (128 rows = 16 groups of 8 rows, 1KB/group)
// A comes straight from global (L2) into registers -- no LDS for A.
#define BBUF  16384
#define SSTR  132         // S-tile row stride in elements (breaks bank conflicts)

typedef short short8 __attribute__((ext_vector_type(8)));
typedef float f32x4 __attribute__((ext_vector_type(4)));

__device__ __forceinline__ uint16_t f2bf(float f) {
  uint32_t u = __builtin_bit_cast(uint32_t, f);
  u += 0x7fffu + ((u >> 16) & 1u);          // round-to-nearest-even
  return (uint16_t)(u >> 16);
}
__device__ __forceinline__ float bf2f(uint32_t h) {   // low 16 bits used
  uint32_t u = h << 16;
  return __builtin_bit_cast(float, u);
}

__device__ __forceinline__ void async_copy16(const void* gsrc, void* ldst) {
  __builtin_amdgcn_global_load_lds(
      (const __attribute__((address_space(1))) uint32_t*)gsrc,
      (__attribute__((address_space(3))) uint32_t*)ldst,
      16, 0, 0);
}

// ------------- prep: cvt x (fp32->bf16) + transpose/cvt B -> Bt -------------
__global__ void prep(const float* __restrict__ x, const float* __restrict__ B,
                     uint16_t* __restrict__ xb, uint16_t* __restrict__ Bt) {
  __shared__ uint16_t tile[64][70];   // stride 70: even (uint2-aligned), ~2-way banks
  const int t = threadIdx.x;
  if (blockIdx.x < 4096) {
    size_t i = ((size_t)blockIdx.x * 256 + t) * 8;
    float4 v0 = *(const float4*)(x + i);
    float4 v1 = *(const float4*)(x + i + 4);
    union { uint16_t h[8]; uint4 v; } o;
    o.h[0] = f2bf(v0.x); o.h[1] = f2bf(v0.y); o.h[2] = f2bf(v0.z); o.h[3] = f2bf(v0.w);
    o.h[4] = f2bf(v1.x); o.h[5] = f2bf(v1.y); o.h[6] = f2bf(v1.z); o.h[7] = f2bf(v1.w);
    *(uint4*)(xb + i) = o.v;
  } else {
    const int bid = blockIdx.x - 4096;
    const int n0 = (bid & 31) * 64;
    const int k0 = (bid >> 5) * 64;
    {
      const int r  = t >> 4;
      const int c4 = (t & 15) * 4;
#pragma unroll
      for (int i = 0; i < 4; ++i) {
        int rr = r + i * 16;
        float4 v = *(const float4*)&B[(size_t)(k0 + rr) * HDIM + n0 + c4];
        union { uint16_t h[4]; uint2 u; } o;
        o.h[0] = f2bf(v.x); o.h[1] = f2bf(v.y); o.h[2] = f2bf(v.z); o.h[3] = f2bf(v.w);
        *(uint2*)&tile[rr][c4] = o.u;
      }
    }
    __syncthreads();
    {
      // 16B stores: 8 threads per Bt row, 128B contiguous per row
      const int nr8 = t >> 3;           // 0..31
      const int kc8 = (t & 7) * 8;      // 0..56
#pragma unroll
      for (int i = 0; i < 2; ++i) {
        int nr = nr8 + i * 32;
        union { uint16_t h[8]; uint4 v; } o;
#pragma unroll
        for (int j = 0; j < 8; ++j) o.h[j] = tile[kc8 + j][nr];
        *(uint4*)&Bt[(size_t)(n0 + nr) * HDIM + k0 + kc8] = o.v;
      }
    }
  }
}

// --------- fused GEMM + causal exp-decay recurrence (scan) ---------
// S[t][n] = sum_k A[t][k]*Bt[n][k]; out[t][h] = S[t][h] + a[h]*out[t-1][h].
// FINDING (R0-R5): every schedule over the A+B LDS pipeline pinned at
// 47-52us (MfmaUtil ~31%) -- traffic, occupancy, phase structure all
// neutral.  The fix is to REMOVE a resource, not reschedule it:
// A-fragments are consumed by one wave each and the A-panel working set
// per XCD is ~2.2MB (L2-resident with the XCD swizzle), so A is loaded
// global->VGPR directly (AITER s02 pattern: buffer_load interleaved with
// MFMA, prefetch distance 1 kt ~ 1500cyc >> L2 latency).  LDS carries B
// only: per-kt-per-CU LDS drops 133KB reads + 50KB writes -> 64KB + 16KB,
// balancing the LDS port (~950cyc) against the MFMA pipe (~1065cyc).
// A-regs double-buffered with STATIC ping-pong (2 kt per loop iter,
// named rA/rB -- rule #20).  512 thr = 8 waves (4Mx2N), 64x64/wave;
// grid 256 = 1 block/CU.  B: 128B rows + XOR-8 swizzle, conflict-free.
// 16 warmup rows on waves 0,1 (direct loads); in-LDS S-tile scan
// epilogue (|a| <= 2^-5 -> a^16 below fp32 noise).
__global__ __launch_bounds__(512, 2) void gemm_scan(
    const uint16_t* __restrict__ A, const uint16_t* __restrict__ Bt,
    const float* __restrict__ a, float* __restrict__ out) {
  __shared__ __align__(16) char lds[71808];   // 2*BBUF K-loop; 272*132*2 epilogue

  const int tid  = threadIdx.x;
  const int lane = tid & 63;
  const int wave = tid >> 6;            // 0..7
  const int wm = (wave >> 1) * 64;      // wave row offset {0,64,128,192}
  const int wn = (wave & 1) * 64;       // wave col offset {0,64}

  // XCD-chunked bijective swizzle: 256 blocks, 8 XCDs, 32 consecutive
  // logical tiles per XCD -> the 16 blocks sharing an A-panel colocate
  // (A-panel: 2 panels x 272 rows x 4KB = 2.2MB per XCD L2).
  const int flat = blockIdx.y * gridDim.x + blockIdx.x;
  const int logi = (flat & 7) * 32 + (flat >> 3);
  const int m0 = (logi >> 4) * BM;      // 16 m-blocks
  const int n0 = (logi & 15) * BN;      // 16 n-blocks

  f32x4 acc[4][4] = {};
  f32x4 accw[4] = {};                   // warmup rows (waves 0,1 only)

  // B staging: one instr = 8 rows x 128B (1KB); lane l: row lr=l>>3,
  // slot l&7, fetches global chunk (l&7)^lr -> LDS slot c holds chunk c^(r&7)
  const int lr = lane >> 3;             // 0..7
  const int gc = (lane & 7) ^ lr;       // swizzled 16B chunk to fetch

  const int fr = lane & 15;
  const int fq = lane >> 4;             // 0..3

  // ---- A direct-load bases (per-lane): frag layout == what the MFMA ate
  // from LDS before: lane(fr,fq) holds A[m0+wm+im*16+fr][kt*64+s*32+fq*8..+8]
  const char* abase = (const char*)A +
      ((size_t)(m0 + wm + fr) * HDIM + fq * 8) * 2;
  int wrow = m0 - 16 + fr; if (wrow < 0) wrow = 0;   // m0==0: garbage, unused
  const char* wbase = (const char*)A + ((size_t)wrow * HDIM + fq * 8) * 2;

  // B: 16 groups of 8 rows; wave w stages groups {2w, 2w+1}.
  auto issueB = [&](int kt2, char* dst) {
    size_t koff = (size_t)kt2 * (BK * 2);
#pragma unroll
    for (int i = 0; i < 2; ++i) {
      int g = wave * 2 + i;
      int row = n0 + g * 8 + lr;
      async_copy16((const char*)Bt + ((size_t)row * HDIM + gc * 8) * 2 + koff,
                   dst + g * 1024);
    }
  };
  // A-frag loads for tile kt2 into nxt (8 x 16B) + warmup (waves 0,1: 2 x 16B)
  auto loadA = [&](int kt2, short8 (&nxt)[4][2], short8 (&awn)[2]) {
    size_t koff = (size_t)kt2 * 128;
#pragma unroll
    for (int im = 0; im < 4; ++im) {
      nxt[im][0] = *(const short8*)(abase + (size_t)im * 16 * HDIM * 2 + koff);
      nxt[im][1] = *(const short8*)(abase + (size_t)im * 16 * HDIM * 2 + koff + 64);
    }
    if (wave < 2) {
      awn[0] = *(const short8*)(wbase + koff);
      awn[1] = *(const short8*)(wbase + koff + 64);
    }
  };

  short8 rA[4][2], rB[4][2], awA[2], awB[2];
  char* buf0 = lds;
  char* buf1 = lds + BBUF;

  // compute one K-tile from cur regs + curbuf; prefetch kt+1 into nxt/nxtbuf
  auto body = [&](int kt, short8 (&cur)[4][2], short8 (&nxt)[4][2],
                  short8 (&awc)[2], short8 (&awn)[2],
                  char* curbuf, char* nxtbuf) {
    if (kt + 1 < NKT) {
      loadA(kt + 1, nxt, awn);
      issueB(kt + 1, nxtbuf);
      // drain B(kt) stage (10/12 ops just issued stay in flight)
      if (wave < 2) asm volatile("s_waitcnt vmcnt(12)" ::: "memory");
      else          asm volatile("s_waitcnt vmcnt(10)" ::: "memory");
    } else {
      asm volatile("s_waitcnt vmcnt(0)" ::: "memory");
    }
    asm volatile("s_barrier" ::: "memory");

#pragma unroll
    for (int s = 0; s < 2; ++s) {
      short8 bfr[4];
#pragma unroll
      for (int in = 0; in < 4; ++in)
        bfr[in] = *(const short8*)(curbuf + (wn + in * 16 + fr) * 128 +
                                   (((s * 4 + fq) ^ (fr & 7)) * 16));
      asm volatile("s_waitcnt lgkmcnt(0)" ::: "memory");
      __builtin_amdgcn_sched_barrier(0);
      __builtin_amdgcn_s_setprio(1);
#pragma unroll
      for (int im = 0; im < 4; ++im)
#pragma unroll
        for (int in = 0; in < 4; ++in)
          acc[im][in] = __builtin_amdgcn_mfma_f32_16x16x32_bf16(
              cur[im][s], bfr[in], acc[im][in], 0, 0, 0);
      if (wave < 2) {
#pragma unroll
        for (int in = 0; in < 4; ++in)
          accw[in] = __builtin_amdgcn_mfma_f32_16x16x32_bf16(
              awc[s], bfr[in], accw[in], 0, 0, 0);
      }
      __builtin_amdgcn_s_setprio(0);
    }
    // all waves' curbuf reads complete (lgkm'd) -> next body may restage it
    asm volatile("s_barrier" ::: "memory");
  };

  // prologue: A(0)->rA, B(0)->buf0
  loadA(0, rA, awA);
  issueB(0, buf0);

#pragma unroll 1
  for (int it = 0; it < NKT / 2; ++it) {
    body(2 * it,     rA, rB, awA, awB, buf0, buf1);
    body(2 * it + 1, rB, rA, awB, awA, buf1, buf0);
  }

  __syncthreads();   // all reads done before S-tile overwrite

  // ---- epilogue: S-tile (272 x 128, bf16, stride 132) into LDS ----
  uint16_t* Sl = (uint16_t*)lds;
#pragma unroll
  for (int im = 0; im < 4; ++im)
#pragma unroll
    for (int in = 0; in < 4; ++in)
#pragma unroll
      for (int r = 0; r < 4; ++r)
        Sl[(16 + wm + im * 16 + fq * 4 + r) * SSTR + wn + in * 16 + fr] =
            f2bf(acc[im][in][r]);
  if (wave < 2) {
#pragma unroll
    for (int in = 0; in < 4; ++in)
#pragma unroll
      for (int r = 0; r < 4; ++r)
        Sl[(fq * 4 + r) * SSTR + wn + in * 16 + fr] = f2bf(accw[in][r]);
  }
  __syncthreads();

  // ---- scan: 4 threads per column, 64 t-steps each, 16-step warmup ----
  const int col   = tid & 127;
  const int chunk = tid >> 7;           // 0..3
  const float av  = a[n0 + col];
  float h = 0.f;
  if (!(m0 == 0 && chunk == 0)) {
#pragma unroll
    for (int i = 0; i < 16; ++i)
      h = av * h + bf2f(Sl[(chunk * 64 + i) * SSTR + col]);
  }
  float* op = out + (size_t)(m0 + chunk * 64) * HDIM + n0 + col;
#pragma unroll
  for (int i = 0; i < 64; ++i) {
    h = av * h + bf2f(Sl[(chunk * 64 + 16 + i) * SSTR + col]);
    op[(size_t)i * HDIM] = h;
  }
}

extern "C" void kernel_launch(void* const* d_in, const int* in_sizes, int n_in,
                              void* d_out, int out_size, void* d_ws, size_t ws_size,
                              hipStream_t stream) {
  const float* x = (const float*)d_in[0];   // (T, H)
  const float* a = (const float*)d_in[1];   // (H,)
  const float* B = (const float*)d_in[2];   // (H, H)
  float* out = (float*)d_out;               // (1, T, H) fp32

  uint16_t* xb  = (uint16_t*)d_ws;                                        // 16 MB
  uint16_t* Btb = (uint16_t*)((char*)d_ws + (size_t)16 * 1024 * 1024);    //  8 MB

  // x -> bf16  and  B -> Bt bf16 (fused)
  prep<<<4096 + 1024, 256, 0, stream>>>(x, B, xb, Btb);
  // fused GEMM + recurrence: 256 blocks x 512 threads (8 waves, 64x64 each)
  gemm_scan<<<dim3(HDIM / BN, TDIM / BM), 512, 0, stream>>>(xb, Btb, a, out);
}

// Round 9
// 160.472 us; speedup vs baseline: 1.1260x; 1.1260x over previous
//
#include <hip/hip_runtime.h>
#include <stdint.h>

// Problem dims
#define TDIM 4096
#define HDIM 2048   // N and K of the GEMM

// GEMM tile
#define BM 256
#define BN 128
#define BK 64
#define NKT (HDIM / BK)   // 32
// LDS per buffer: A region (272 rows = 34 groups of 8 rows, 1KB/group)
//               + B region (128 rows = 16 groups), 128B per row (BK=64 bf16)
#define AREG  34816
#define PERBUF 51200
#define SSTR   132        // S-tile row stride in elements (breaks bank conflicts)

typedef short short8 __attribute__((ext_vector_type(8)));
typedef float f32x4 __attribute__((ext_vector_type(4)));

__device__ __forceinline__ uint16_t f2bf(float f) {
  uint32_t u = __builtin_bit_cast(uint32_t, f);
  u += 0x7fffu + ((u >> 16) & 1u);          // round-to-nearest-even
  return (uint16_t)(u >> 16);
}
__device__ __forceinline__ float bf2f(uint32_t h) {   // low 16 bits used
  uint32_t u = h << 16;
  return __builtin_bit_cast(float, u);
}

__device__ __forceinline__ void async_copy16(const void* gsrc, void* ldst) {
  __builtin_amdgcn_global_load_lds(
      (const __attribute__((address_space(1))) uint32_t*)gsrc,
      (__attribute__((address_space(3))) uint32_t*)ldst,
      16, 0, 0);
}

// ------------- prep_b: transpose/cvt B -> Bt (bf16) only -------------
// (x is consumed as f32 directly by gemm_scan -- the x->bf16 pass is gone)
__global__ void prep_b(const float* __restrict__ B, uint16_t* __restrict__ Bt) {
  __shared__ uint16_t tile[64][70];   // stride 70: even (uint2-aligned), ~2-way banks
  const int t = threadIdx.x;
  const int bid = blockIdx.x;
  const int n0 = (bid & 31) * 64;
  const int k0 = (bid >> 5) * 64;
  {
    const int r  = t >> 4;
    const int c4 = (t & 15) * 4;
#pragma unroll
    for (int i = 0; i < 4; ++i) {
      int rr = r + i * 16;
      float4 v = *(const float4*)&B[(size_t)(k0 + rr) * HDIM + n0 + c4];
      union { uint16_t h[4]; uint2 u; } o;
      o.h[0] = f2bf(v.x); o.h[1] = f2bf(v.y); o.h[2] = f2bf(v.z); o.h[3] = f2bf(v.w);
      *(uint2*)&tile[rr][c4] = o.u;
    }
  }
  __syncthreads();
  {
    // 16B stores: 8 threads per Bt row, 128B contiguous per row
    const int nr8 = t >> 3;           // 0..31
    const int kc8 = (t & 7) * 8;      // 0..56
#pragma unroll
    for (int i = 0; i < 2; ++i) {
      int nr = nr8 + i * 32;
      union { uint16_t h[8]; uint4 v; } o;
#pragma unroll
      for (int j = 0; j < 8; ++j) o.h[j] = tile[kc8 + j][nr];
      *(uint4*)&Bt[(size_t)(n0 + nr) * HDIM + k0 + kc8] = o.v;
    }
  }
}

// --------- fused GEMM + causal exp-decay recurrence (scan) ---------
// S[t][n] = sum_k x[t][k]*Bt[n][k]; out[t][h] = S[t][h] + a[h]*out[t-1][h].
// R0-R6 findings: gemm pinned 47-52us across traffic/occupancy/schedule
// variants; per-lane fragment loads from global (R6) shatter coalescing.
// This round: A staged from f32 x DIRECTLY (x->bf16 prep pass deleted).
// Same group-staging geometry as the proven kernel -- lane l of a group
// loads 8 consecutive f32 (2x float4; 8 lanes = 256B coalesced row seg),
// cvts (same RNE f2bf as prep used -> bit-identical), ds_write_b128 to the
// identical XOR-8-swizzled LDS slot.  T14 split: A-loads for kt+1 issue at
// top of kt, cvt+write lands after kt's MFMAs (~2500cyc of cover).
// ONE barrier per kt: buf[nxt] writers (kt) ordered after its kt-1
// readers by the kt-1 barrier.  B via global_load_lds from Btb (bf16).
// 512 thr = 8 waves (4Mx2N), 64x64/wave; grid 256 = 1 block/CU.
// 16 warmup rows on waves 0,1; in-LDS S-tile scan epilogue (|a| <= 2^-5).
__global__ __launch_bounds__(512, 2) void gemm_scan(
    const float* __restrict__ X, const uint16_t* __restrict__ Bt,
    const float* __restrict__ a, float* __restrict__ out) {
  __shared__ __align__(16) char lds[2 * PERBUF];   // 102400

  const int tid  = threadIdx.x;
  const int lane = tid & 63;
  const int wave = tid >> 6;            // 0..7
  const int wm = (wave >> 1) * 64;      // wave row offset {0,64,128,192}
  const int wn = (wave & 1) * 64;       // wave col offset {0,64}

  // XCD-chunked bijective swizzle: 256 blocks, 8 XCDs, 32 consecutive
  // logical tiles per XCD -> the 16 blocks sharing an A-panel colocate.
  const int flat = blockIdx.y * gridDim.x + blockIdx.x;
  const int logi = (flat & 7) * 32 + (flat >> 3);
  const int m0 = (logi >> 4) * BM;      // 16 m-blocks
  const int n0 = (logi & 15) * BN;      // 16 n-blocks

  f32x4 acc[4][4] = {};
  f32x4 accw[4] = {};                   // warmup rows (waves 0,1 only)

  // staging lane roles: group = 8 rows x 64 k (1KB bf16 in LDS).
  // lane l: row-in-group lr = l>>3, k-chunk lc = l&7 (8 f32 = 32B global).
  // ds_write slot (lc^lr) -> LDS slot c of row r holds chunk c^(r&7),
  // matching the MFMA-side read swizzle ((s*4+fq)^(fr&7)).
  const int lr = lane >> 3;             // 0..7
  const int lc = lane & 7;              // k-chunk index
  const int gcB = lc ^ lr;              // B staging: swizzled chunk to fetch

  const int fr = lane & 15;
  const int fq = lane >> 4;             // 0..3

  // A: 34 groups of 8 rows (t in [m0-16, m0+256)); wave w takes g=4w..4w+3,
  // waves 0,1 additionally g=32,33.  B: 16 groups; wave w takes 2w,2w+1.
  float4 ar[4][2];                      // A f32 staging regs (4 groups)
  float4 are[2];                        // extra group (waves 0,1)

  auto loadA = [&](int kt2) {
    const float* xk = X + (size_t)kt2 * BK + lc * 8;
#pragma unroll
    for (int i = 0; i < 4; ++i) {
      int g = wave * 4 + i;
      int row = m0 - 16 + g * 8 + lr;
      if (row < 0) row = 0;             // m0==0: garbage rows, never used
      const float* p = xk + (size_t)row * HDIM;
      ar[i][0] = *(const float4*)p;
      ar[i][1] = *(const float4*)(p + 4);
    }
    if (wave < 2) {
      int g = 32 + wave;
      int row = m0 - 16 + g * 8 + lr;   // rows m0+240..m0+255: always valid
      const float* p = xk + (size_t)row * HDIM;
      are[0] = *(const float4*)p;
      are[1] = *(const float4*)(p + 4);
    }
  };
  auto writeA = [&](char* dst) {
    const int wslot = (lc ^ lr) * 16;
#pragma unroll
    for (int i = 0; i < 4; ++i) {
      int g = wave * 4 + i;
      union { uint16_t h[8]; uint4 v; } o;
#pragma unroll
      for (int j = 0; j < 4; ++j) o.h[j] = f2bf(ar[i][0][j]);
#pragma unroll
      for (int j = 0; j < 4; ++j) o.h[4 + j] = f2bf(ar[i][1][j]);
      *(uint4*)(dst + g * 1024 + lr * 128 + wslot) = o.v;
    }
    if (wave < 2) {
      int g = 32 + wave;
      union { uint16_t h[8]; uint4 v; } o;
#pragma unroll
      for (int j = 0; j < 4; ++j) o.h[j] = f2bf(are[0][j]);
#pragma unroll
      for (int j = 0; j < 4; ++j) o.h[4 + j] = f2bf(are[1][j]);
      *(uint4*)(dst + g * 1024 + lr * 128 + wslot) = o.v;
    }
  };
  auto issueB = [&](int kt2, char* dst) {
    size_t koff = (size_t)kt2 * (BK * 2);
#pragma unroll
    for (int i = 0; i < 2; ++i) {
      int g = wave * 2 + i;
      int row = n0 + g * 8 + lr;
      async_copy16((const char*)Bt + ((size_t)row * HDIM + gcB * 8) * 2 + koff,
                   dst + AREG + g * 1024);
    }
  };

  char* buf0 = lds;
  char* buf1 = lds + PERBUF;

  // prologue: stage tile 0 (A: load+cvt+write; B: DMA), then barrier
  loadA(0);
  issueB(0, buf0);
  writeA(buf0);                                   // compiler waits A vmcnt
  asm volatile("s_waitcnt lgkmcnt(0)" ::: "memory");   // A writes visible
  asm volatile("s_waitcnt vmcnt(0)" ::: "memory");     // B DMA arrived
  asm volatile("s_barrier" ::: "memory");

  for (int kt = 0; kt < NKT; ++kt) {
    char* cur = (kt & 1) ? buf1 : buf0;
    char* nxt = (kt & 1) ? buf0 : buf1;
    const bool pf = (kt + 1 < NKT);

    // issue next tile's staging first: A f32 -> regs, B -> LDS DMA.
    // Latency hides under this kt's ds_read+MFMA (~2500 cyc).
    if (pf) { loadA(kt + 1); issueB(kt + 1, nxt); }

#pragma unroll
    for (int s = 0; s < 2; ++s) {       // two K=32 halves of the 128B row
      short8 af[4], bfr[4], aw;
#pragma unroll
      for (int im = 0; im < 4; ++im)
        af[im] = *(const short8*)(cur + (16 + wm + im * 16 + fr) * 128 +
                                  (((s * 4 + fq) ^ (fr & 7)) * 16));
#pragma unroll
      for (int in = 0; in < 4; ++in)
        bfr[in] = *(const short8*)(cur + AREG + (wn + in * 16 + fr) * 128 +
                                   (((s * 4 + fq) ^ (fr & 7)) * 16));
      aw = af[0];
      if (wave < 2)
        aw = *(const short8*)(cur + fr * 128 + (((s * 4 + fq) ^ (fr & 7)) * 16));
      asm volatile("s_waitcnt lgkmcnt(0)" ::: "memory");
      __builtin_amdgcn_sched_barrier(0);
      __builtin_amdgcn_s_setprio(1);
#pragma unroll
      for (int im = 0; im < 4; ++im)
#pragma unroll
        for (int in = 0; in < 4; ++in)
          acc[im][in] = __builtin_amdgcn_mfma_f32_16x16x32_bf16(
              af[im], bfr[in], acc[im][in], 0, 0, 0);
      if (wave < 2) {
#pragma unroll
        for (int in = 0; in < 4; ++in)
          accw[in] = __builtin_amdgcn_mfma_f32_16x16x32_bf16(
              aw, bfr[in], accw[in], 0, 0, 0);
      }
      __builtin_amdgcn_s_setprio(0);
    }

    if (pf) {
      // cvt + ds_write A(kt+1) into nxt.  Safe: nxt's kt-1 readers finished
      // before the barrier that opened this kt.  Compiler inserts the exact
      // vmcnt for the f32 regs (B's 2 DMA ops, issued later, stay in flight
      // until the explicit vmcnt(0) below -- long since arrived).
      writeA(nxt);
      asm volatile("s_waitcnt lgkmcnt(0)" ::: "memory");  // writes visible
      asm volatile("s_waitcnt vmcnt(0)" ::: "memory");    // B(kt+1) arrived
    }
    asm volatile("s_barrier" ::: "memory");
  }

  // ---- epilogue: S-tile (272 x 128, bf16, stride 132) into LDS ----
  uint16_t* Sl = (uint16_t*)lds;
#pragma unroll
  for (int im = 0; im < 4; ++im)
#pragma unroll
    for (int in = 0; in < 4; ++in)
#pragma unroll
      for (int r = 0; r < 4; ++r)
        Sl[(16 + wm + im * 16 + fq * 4 + r) * SSTR + wn + in * 16 + fr] =
            f2bf(acc[im][in][r]);
  if (wave < 2) {
#pragma unroll
    for (int in = 0; in < 4; ++in)
#pragma unroll
      for (int r = 0; r < 4; ++r)
        Sl[(fq * 4 + r) * SSTR + wn + in * 16 + fr] = f2bf(accw[in][r]);
  }
  __syncthreads();

  // ---- scan: 4 threads per column, 64 t-steps each, 16-step warmup ----
  const int col   = tid & 127;
  const int chunk = tid >> 7;           // 0..3
  const float av  = a[n0 + col];
  float h = 0.f;
  if (!(m0 == 0 && chunk == 0)) {
#pragma unroll
    for (int i = 0; i < 16; ++i)
      h = av * h + bf2f(Sl[(chunk * 64 + i) * SSTR + col]);
  }
  float* op = out + (size_t)(m0 + chunk * 64) * HDIM + n0 + col;
#pragma unroll
  for (int i = 0; i < 64; ++i) {
    h = av * h + bf2f(Sl[(chunk * 64 + 16 + i) * SSTR + col]);
    op[(size_t)i * HDIM] = h;
  }
}

extern "C" void kernel_launch(void* const* d_in, const int* in_sizes, int n_in,
                              void* d_out, int out_size, void* d_ws, size_t ws_size,
                              hipStream_t stream) {
  const float* x = (const float*)d_in[0];   // (T, H)
  const float* a = (const float*)d_in[1];   // (H,)
  const float* B = (const float*)d_in[2];   // (H, H)
  float* out = (float*)d_out;               // (1, T, H) fp32

  uint16_t* Btb = (uint16_t*)d_ws;          // 8 MB (x is consumed as f32)

  // B -> Bt bf16 (transpose) -- the only prep pass left
  prep_b<<<1024, 256, 0, stream>>>(B, Btb);
  // fused GEMM + recurrence: 256 blocks x 512 threads (8 waves, 64x64 each)
  gemm_scan<<<dim3(HDIM / BN, TDIM / BM), 512, 0, stream>>>(x, Btb, a, out);
}

// Round 10
// 137.358 us; speedup vs baseline: 1.3155x; 1.1683x over previous
//
#include <hip/hip_runtime.h>
#include <stdint.h>

// Problem dims
#define TDIM 4096
#define HDIM 2048   // N and K of the GEMM

// GEMM tile
#define BM 256
#define BN 128
#define BK 64
#define NKT (HDIM / BK)   // 32
// LDS: per buffer = A region (272 rows = 34 groups of 8 rows, 1KB/group)
//      + B region (128 rows = 16 groups), 128B per row (BK=64 bf16)
#define AREG  34816
#define PERBUF 51200
#define SSTR   132        // S-tile row stride in elements (breaks bank conflicts)

typedef short short8 __attribute__((ext_vector_type(8)));
typedef float f32x4 __attribute__((ext_vector_type(4)));

__device__ __forceinline__ uint16_t f2bf(float f) {
  uint32_t u = __builtin_bit_cast(uint32_t, f);
  u += 0x7fffu + ((u >> 16) & 1u);          // round-to-nearest-even
  return (uint16_t)(u >> 16);
}
__device__ __forceinline__ float bf2f(uint32_t h) {   // low 16 bits used
  uint32_t u = h << 16;
  return __builtin_bit_cast(float, u);
}

__device__ __forceinline__ void async_copy16(const void* gsrc, void* ldst) {
  __builtin_amdgcn_global_load_lds(
      (const __attribute__((address_space(1))) uint32_t*)gsrc,
      (__attribute__((address_space(3))) uint32_t*)ldst,
      16, 0, 0);
}

// ------------- prep: cvt x (fp32->bf16) + transpose/cvt B -> Bt -------------
__global__ void prep(const float* __restrict__ x, const float* __restrict__ B,
                     uint16_t* __restrict__ xb, uint16_t* __restrict__ Bt) {
  __shared__ uint16_t tile[64][70];   // stride 70: even (uint2-aligned), ~2-way banks
  const int t = threadIdx.x;
  if (blockIdx.x < 4096) {
    size_t i = ((size_t)blockIdx.x * 256 + t) * 8;
    float4 v0 = *(const float4*)(x + i);
    float4 v1 = *(const float4*)(x + i + 4);
    union { uint16_t h[8]; uint4 v; } o;
    o.h[0] = f2bf(v0.x); o.h[1] = f2bf(v0.y); o.h[2] = f2bf(v0.z); o.h[3] = f2bf(v0.w);
    o.h[4] = f2bf(v1.x); o.h[5] = f2bf(v1.y); o.h[6] = f2bf(v1.z); o.h[7] = f2bf(v1.w);
    *(uint4*)(xb + i) = o.v;
  } else {
    const int bid = blockIdx.x - 4096;
    const int n0 = (bid & 31) * 64;
    const int k0 = (bid >> 5) * 64;
    {
      const int r  = t >> 4;
      const int c4 = (t & 15) * 4;
#pragma unroll
      for (int i = 0; i < 4; ++i) {
        int rr = r + i * 16;
        float4 v = *(const float4*)&B[(size_t)(k0 + rr) * HDIM + n0 + c4];
        union { uint16_t h[4]; uint2 u; } o;
        o.h[0] = f2bf(v.x); o.h[1] = f2bf(v.y); o.h[2] = f2bf(v.z); o.h[3] = f2bf(v.w);
        *(uint2*)&tile[rr][c4] = o.u;
      }
    }
    __syncthreads();
    {
      // 16B stores: 8 threads per Bt row, 128B contiguous per row
      const int nr8 = t >> 3;           // 0..31
      const int kc8 = (t & 7) * 8;      // 0..56
#pragma unroll
      for (int i = 0; i < 2; ++i) {
        int nr = nr8 + i * 32;
        union { uint16_t h[8]; uint4 v; } o;
#pragma unroll
        for (int j = 0; j < 8; ++j) o.h[j] = tile[kc8 + j][nr];
        *(uint4*)&Bt[(size_t)(n0 + nr) * HDIM + k0 + kc8] = o.v;
      }
    }
  }
}

// --------- fused GEMM + causal exp-decay recurrence (scan) ---------
// S[t][n] = sum_k A[t][k]*Bt[n][k]; out[t][h] = S[t][h] + a[h]*out[t-1][h].
// BEST MEASURED CONFIG (137.08us total, gemm 47.4us) -- restored after
// R4-R9 explored occupancy (x2: null), 4-phase/triple-buffer (null),
// A-from-L2 reg paths (R6/R9: -40-80% regressions).  Findings: gemm is
// latency-structure-bound at ~47us (no pipe >35%); prep is BW-bound;
// ~70us of total is fixed harness overhead.
// 512 threads = 8 waves (4M x 2N), 64x64 per wave (occupancy-forced).
// BM=256: B-panel staged once per 256 M-rows; grid 256 = 1 block/CU,
// 2 waves/SIMD.  Phase-split schedule (T3/T4/T5): per K-tile two phases,
// each {stage-issue | counted vmcnt | barrier | ds_read | lgkmcnt(0)+
// sched_barrier | setprio(1) MFMA cluster setprio(0)}.
// BK=64: 128B rows + XOR-8 chunk swizzle = conflict-free.
// 16 warmup rows on waves 0,1; in-LDS S-tile scan epilogue (|a| <= 2^-5).
__global__ __launch_bounds__(512, 2) void gemm_scan(
    const uint16_t* __restrict__ A, const uint16_t* __restrict__ Bt,
    const float* __restrict__ a, float* __restrict__ out) {
  __shared__ __align__(16) char lds[2 * PERBUF];   // 102400

  const int tid  = threadIdx.x;
  const int lane = tid & 63;
  const int wave = tid >> 6;            // 0..7
  const int wm = (wave >> 1) * 64;      // wave row offset {0,64,128,192}
  const int wn = (wave & 1) * 64;       // wave col offset {0,64}

  // XCD-chunked bijective swizzle: 256 blocks, 8 XCDs, 32 consecutive
  // logical tiles per XCD -> the 16 blocks sharing an A-panel colocate.
  const int flat = blockIdx.y * gridDim.x + blockIdx.x;
  const int logi = (flat & 7) * 32 + (flat >> 3);
  const int m0 = (logi >> 4) * BM;      // 16 m-blocks
  const int n0 = (logi & 15) * BN;      // 16 n-blocks

  f32x4 acc[4][4] = {};
  f32x4 accw[4] = {};                   // warmup rows (waves 0,1 only)

  // staging: one instr = 8 rows x 128B (1KB); lane l: row lr=l>>3, slot l&7,
  // fetches global chunk (l&7)^lr -> LDS slot c of row r holds chunk c^(r&7)
  const int lr = lane >> 3;             // 0..7
  const int gc = (lane & 7) ^ lr;       // swizzled 16B chunk to fetch

  const int fr = lane & 15;
  const int fq = lane >> 4;             // 0..3

  // A: 34 groups of 8 rows (t in [m0-16, m0+256)); wave w takes g=4w..4w+3
  // (phase 0); B: 16 groups, wave w takes 2w,2w+1; waves 0,1 also take
  // A groups 32,33 (phase 1).  Uniform 4 loads in phase 0 -> vmcnt(4).
  auto issue_A = [&](int kt2) {
    size_t koff = (size_t)kt2 * (BK * 2);
    char* dst = lds + (kt2 & 1) * PERBUF;
#pragma unroll
    for (int i = 0; i < 4; ++i) {
      int g = wave * 4 + i;
      int row = m0 - 16 + g * 8 + lr;
      if (row < 0) row = 0;             // m0==0: garbage rows, never used
      async_copy16((const char*)A + ((size_t)row * HDIM + gc * 8) * 2 + koff,
                   dst + g * 1024);
    }
  };
  auto issue_B = [&](int kt2) {
    size_t koff = (size_t)kt2 * (BK * 2);
    char* dst = lds + (kt2 & 1) * PERBUF;
#pragma unroll
    for (int i = 0; i < 2; ++i) {
      int g = wave * 2 + i;
      int row = n0 + g * 8 + lr;
      async_copy16((const char*)Bt + ((size_t)row * HDIM + gc * 8) * 2 + koff,
                   dst + AREG + g * 1024);
    }
    if (wave < 2) {
      int g = 32 + wave;
      int row = m0 - 16 + g * 8 + lr;   // rows m0+240..m0+255: always valid
      async_copy16((const char*)A + ((size_t)row * HDIM + gc * 8) * 2 + koff,
                   dst + g * 1024);
    }
  };

  issue_A(0);
  issue_B(0);

  for (int kt = 0; kt < NKT; ++kt) {
    const char* base = lds + (kt & 1) * PERBUF;

    // ---------- phase 0: K-half s=0 ----------
    if (kt + 1 < NKT) {
      issue_A(kt + 1);
      // wait this tile's loads; the 4 just-issued stay in flight
      asm volatile("s_waitcnt vmcnt(4)" ::: "memory");
    } else {
      asm volatile("s_waitcnt vmcnt(0)" ::: "memory");
    }
    asm volatile("s_barrier" ::: "memory");
    {
      short8 af[4], bfr[4];
#pragma unroll
      for (int im = 0; im < 4; ++im)
        af[im] = *(const short8*)(base + (16 + wm + im * 16 + fr) * 128 +
                                  ((fq ^ (fr & 7)) * 16));
#pragma unroll
      for (int in = 0; in < 4; ++in)
        bfr[in] = *(const short8*)(base + AREG + (wn + in * 16 + fr) * 128 +
                                   ((fq ^ (fr & 7)) * 16));
      short8 aw = af[0];
      if (wave < 2)
        aw = *(const short8*)(base + fr * 128 + ((fq ^ (fr & 7)) * 16));
      asm volatile("s_waitcnt lgkmcnt(0)" ::: "memory");
      __builtin_amdgcn_sched_barrier(0);
      __builtin_amdgcn_s_setprio(1);
#pragma unroll
      for (int im = 0; im < 4; ++im)
#pragma unroll
        for (int in = 0; in < 4; ++in)
          acc[im][in] = __builtin_amdgcn_mfma_f32_16x16x32_bf16(
              af[im], bfr[in], acc[im][in], 0, 0, 0);
      if (wave < 2) {
#pragma unroll
        for (int in = 0; in < 4; ++in)
          accw[in] = __builtin_amdgcn_mfma_f32_16x16x32_bf16(
              aw, bfr[in], accw[in], 0, 0, 0);
      }
      __builtin_amdgcn_s_setprio(0);
    }

    // ---------- phase 1: K-half s=1 ----------
    {
      short8 af[4], bfr[4];
#pragma unroll
      for (int im = 0; im < 4; ++im)
        af[im] = *(const short8*)(base + (16 + wm + im * 16 + fr) * 128 +
                                  (((4 + fq) ^ (fr & 7)) * 16));
#pragma unroll
      for (int in = 0; in < 4; ++in)
        bfr[in] = *(const short8*)(base + AREG + (wn + in * 16 + fr) * 128 +
                                   (((4 + fq) ^ (fr & 7)) * 16));
      short8 aw = af[0];
      if (wave < 2)
        aw = *(const short8*)(base + fr * 128 + (((4 + fq) ^ (fr & 7)) * 16));
      if (kt + 1 < NKT) issue_B(kt + 1);
      // barrier AFTER the reads: next iter re-stages this buffer only once
      // every wave's reads are enqueued; read latency hides under barrier.
      asm volatile("s_barrier" ::: "memory");
      asm volatile("s_waitcnt lgkmcnt(0)" ::: "memory");
      __builtin_amdgcn_sched_barrier(0);
      __builtin_amdgcn_s_setprio(1);
#pragma unroll
      for (int im = 0; im < 4; ++im)
#pragma unroll
        for (int in = 0; in < 4; ++in)
          acc[im][in] = __builtin_amdgcn_mfma_f32_16x16x32_bf16(
              af[im], bfr[in], acc[im][in], 0, 0, 0);
      if (wave < 2) {
#pragma unroll
        for (int in = 0; in < 4; ++in)
          accw[in] = __builtin_amdgcn_mfma_f32_16x16x32_bf16(
              aw, bfr[in], accw[in], 0, 0, 0);
      }
      __builtin_amdgcn_s_setprio(0);
    }
  }

  __syncthreads();   // all reads of both buffers done before S-tile overwrite

  // ---- epilogue: S-tile (272 x 128, bf16, stride 132) into LDS ----
  uint16_t* Sl = (uint16_t*)lds;
#pragma unroll
  for (int im = 0; im < 4; ++im)
#pragma unroll
    for (int in = 0; in < 4; ++in)
#pragma unroll
      for (int r = 0; r < 4; ++r)
        Sl[(16 + wm + im * 16 + fq * 4 + r) * SSTR + wn + in * 16 + fr] =
            f2bf(acc[im][in][r]);
  if (wave < 2) {
#pragma unroll
    for (int in = 0; in < 4; ++in)
#pragma unroll
      for (int r = 0; r < 4; ++r)
        Sl[(fq * 4 + r) * SSTR + wn + in * 16 + fr] = f2bf(accw[in][r]);
  }
  __syncthreads();

  // ---- scan: 4 threads per column, 64 t-steps each, 16-step warmup ----
  const int col   = tid & 127;
  const int chunk = tid >> 7;           // 0..3
  const float av  = a[n0 + col];
  float h = 0.f;
  if (!(m0 == 0 && chunk == 0)) {
#pragma unroll
    for (int i = 0; i < 16; ++i)
      h = av * h + bf2f(Sl[(chunk * 64 + i) * SSTR + col]);
  }
  float* op = out + (size_t)(m0 + chunk * 64) * HDIM + n0 + col;
#pragma unroll
  for (int i = 0; i < 64; ++i) {
    h = av * h + bf2f(Sl[(chunk * 64 + 16 + i) * SSTR + col]);
    op[(size_t)i * HDIM] = h;
  }
}

extern "C" void kernel_launch(void* const* d_in, const int* in_sizes, int n_in,
                              void* d_out, int out_size, void* d_ws, size_t ws_size,
                              hipStream_t stream) {
  const float* x = (const float*)d_in[0];   // (T, H)
  const float* a = (const float*)d_in[1];   // (H,)
  const float* B = (const float*)d_in[2];   // (H, H)
  float* out = (float*)d_out;               // (1, T, H) fp32

  uint16_t* xb  = (uint16_t*)d_ws;                                        // 16 MB
  uint16_t* Btb = (uint16_t*)((char*)d_ws + (size_t)16 * 1024 * 1024);    //  8 MB

  // x -> bf16  and  B -> Bt bf16 (fused)
  prep<<<4096 + 1024, 256, 0, stream>>>(x, B, xb, Btb);
  // fused GEMM + recurrence: 256 blocks x 512 threads (8 waves, 64x64 each)
  gemm_scan<<<dim3(HDIM / BN, TDIM / BM), 512, 0, stream>>>(xb, Btb, a, out);
}